// Round 9
// baseline (35.564 us; speedup 1.0000x reference)
//
#include <hip/hip_runtime.h>

namespace {

constexpr int N  = 50000;
constexpr int R  = 10;
constexpr int DD = 5;
constexpr int RN = R * N;        // 500000
constexpr int DN = DD * N;       // 250000
constexpr int E  = 10000000;
constexpr int EP = E / 2;        // edge pairs (int4 loads)
constexpr int EPH = EP / 2;      // per-stream half

// bitmask geometry
constexpr int ZB_BLOCKS = (DN + 255) / 256;          // 977
constexpr int ZB_WORDS  = ZB_BLOCKS * 256 / 32;      // 7816 u32 (31264 B)

// K1 partition: bits + psc seed (syn algebra) + neuron
constexpr int SEED_BLOCKS = (RN / 4 + 255) / 256;    // 489
constexpr int NEUR_BLOCKS = (N + 255) / 256;         // 196
constexpr int PRE_BLOCKS  = ZB_BLOCKS + SEED_BLOCKS + NEUR_BLOCKS;

// scatter: 512-thread blocks, 4 blocks/CU co-resident
constexpr int SC_BLOCK = 512;
constexpr int SC_GRID  = 1024;
constexpr int GS       = SC_GRID * SC_BLOCK;         // 524288
constexpr int NITER    = (EPH + GS - 1) / GS;        // 5
constexpr int QCAP     = 128;                        // entries per wave queue

// ---------------------------------------------------------------------------
// K1: spike bitmask + psc_rise/psc outputs (seeded, pre-scatter) + neuron.
__global__ __launch_bounds__(256) void pre_kernel(
    const float*  __restrict__ z_buf,
    unsigned int* __restrict__ bits,
    const float4* __restrict__ inputs4,
    const float*  __restrict__ psc_rise,
    const float*  __restrict__ psc,
    const float*  __restrict__ syn_decay,
    const float*  __restrict__ psc_initial,
    const float*  __restrict__ v,
    const float*  __restrict__ r,
    const float*  __restrict__ asc1,
    const float*  __restrict__ asc2,
    const float*  __restrict__ v_th,
    const float*  __restrict__ e_l,
    const float*  __restrict__ v_reset,
    const float*  __restrict__ g,
    const float*  __restrict__ decay,
    const float*  __restrict__ current_factor,
    const float*  __restrict__ t_ref,
    const float2* __restrict__ k,
    const float2* __restrict__ asc_amps,
    const float*  __restrict__ voltage_scale,
    const float*  __restrict__ voltage_offset,
    float*        __restrict__ out)
{
    int b = blockIdx.x;
    int tid = threadIdx.x;

    if (b < ZB_BLOCKS) {
        int i = b * 256 + tid;
        float zv = (i < DN) ? z_buf[i] : 0.0f;
        unsigned long long m = __ballot(zv != 0.0f);
        if ((tid & 63) == 0) {
            int w = i >> 5;
            bits[w]     = (unsigned int)m;
            bits[w + 1] = (unsigned int)(m >> 32);
        }
        return;
    }
    b -= ZB_BLOCKS;
    if (b < SEED_BLOCKS) {
        int j = b * 256 + tid;
        if (j >= RN / 4) return;
        const float4* pr4 = reinterpret_cast<const float4*>(psc_rise);
        const float4* ps4 = reinterpret_cast<const float4*>(psc);
        const float4* sd4 = reinterpret_cast<const float4*>(syn_decay);
        const float4* pi4 = reinterpret_cast<const float4*>(psc_initial);
        float4* opr4 = reinterpret_cast<float4*>(out + 11 * N);
        float4* ops4 = reinterpret_cast<float4*>(out + 21 * N);
        float4 sd = sd4[j];
        float4 pr = pr4[j];
        float4 pi = pi4[j];
        float4 in = inputs4[j];
        float4 ps = ps4[j];
        float4 opr, ops;
        opr.x = sd.x * pr.x + in.x * pi.x;
        opr.y = sd.y * pr.y + in.y * pi.y;
        opr.z = sd.z * pr.z + in.z * pi.z;
        opr.w = sd.w * pr.w + in.w * pi.w;
        ops.x = ps.x * sd.x + sd.x * pr.x;
        ops.y = ps.y * sd.y + sd.y * pr.y;
        ops.z = ps.z * sd.z + sd.z * pr.z;
        ops.w = ps.w * sd.w + sd.w * pr.w;
        opr4[j] = opr;
        ops4[j] = ops;
        return;
    }
    b -= SEED_BLOCKS;
    {
        int n = b * 256 + tid;
        if (n >= N) return;

        float prev_z = z_buf[n];

        const float2* p2 = reinterpret_cast<const float2*>(psc + n * R);
        float ic = 0.0f;
#pragma unroll
        for (int t = 0; t < R / 2; ++t) {
            float2 pp = p2[t];
            ic += pp.x + pp.y;
        }

        float new_r = fmaxf(r[n] + prev_z * t_ref[n] - 1.0f, 0.0f);   // DT=1

        float2 kk = k[n];
        float2 aa = asc_amps[n];
        float s0 = 1.0f / (1.0f + expf(-kk.x));
        float s1 = 1.0f / (1.0f + expf(-kk.y));
        float a1_old = asc1[n];
        float a2_old = asc2[n];
        float new_a1 = expf(-s0) * a1_old + prev_z * aa.x;
        float new_a2 = expf(-s1) * a2_old + prev_z * aa.y;

        float el = e_l[n];
        float new_v = decay[n] * v[n]
                    + current_factor[n] * (ic + a1_old + a2_old + g[n] * el);

        float vth = v_th[n];
        float v_sc = (new_v - vth) / (vth - el);
        float nz = (v_sc > 0.0f) ? 1.0f : 0.0f;
        if (new_r > 0.0f) nz = 0.0f;
        if (nz > 0.5f) new_v = v_reset[n];

        out[0 * N + n]  = nz;
        out[1 * N + n]  = new_v * voltage_scale[n] + voltage_offset[n];
        out[2 * N + n]  = nz;
        out[7 * N + n]  = new_v;
        out[8 * N + n]  = new_r;
        out[9 * N + n]  = new_a1;
        out[10 * N + n] = new_a2;
    }
}

// ---------------------------------------------------------------------------
// K2: streaming scatter with ballot-compaction queue.
// Hot loop: pure idx stream + LDS bit tests + LDS queue writes (no divergent
// VMEM). Dense 64-wide flushes do rec_w*pinit atomicAdd into out_psc_rise.
__global__ __launch_bounds__(SC_BLOCK) void scatter_kernel(
    const float* __restrict__ rec_w,
    const int4*  __restrict__ idx4,          // [p] = (row0, col0, row1, col1)
    const unsigned int* __restrict__ bits_g,
    const float* __restrict__ pinit,
    const float* __restrict__ z_buf,
    float*       __restrict__ out)
{
    __shared__ unsigned int bits[ZB_WORDS];
    __shared__ uint2 queue[SC_BLOCK / 64][QCAP];
    {
        const uint4* src = reinterpret_cast<const uint4*>(bits_g);
        uint4* dst = reinterpret_cast<uint4*>(bits);
        for (int i = threadIdx.x; i < ZB_WORDS / 4; i += SC_BLOCK)
            dst[i] = src[i];
    }
    __syncthreads();

    float* opr = out + 11 * N;

    const int wv   = threadIdx.x >> 6;
    const int lane = threadIdx.x & 63;
    uint2* q = queue[wv];

    unsigned int head = 0, tail = 0;   // wave-uniform

    const int gid = blockIdx.x * SC_BLOCK + threadIdx.x;

    auto enq = [&](unsigned int e, unsigned int row, bool act) {
        unsigned long long mask = __ballot(act);
        if (mask) {
            unsigned int off = __builtin_amdgcn_mbcnt_hi(
                (unsigned int)(mask >> 32),
                __builtin_amdgcn_mbcnt_lo((unsigned int)mask, 0));
            if (act) q[(tail + off) & (QCAP - 1)] = make_uint2(e, row);
            tail += (unsigned int)__popcll(mask);
        }
    };
    auto flush64 = [&]() {
        uint2 ent = q[(head + lane) & (QCAP - 1)];
        atomicAdd(opr + ent.y, rec_w[ent.x] * pinit[ent.y]);
        head += 64;
    };

    int pA = gid;
    int pB = gid + EPH;
#pragma unroll
    for (int it = 0; it < NITER; ++it) {
        bool hA = pA < EPH;
        bool hB = pB < EP;
        int4 a = hA ? idx4[pA] : make_int4(0, 0, 0, 0);
        int4 b = hB ? idx4[pB] : make_int4(0, 0, 0, 0);

        bool a0 = hA && ((bits[a.y >> 5] >> (a.y & 31)) & 1u);
        bool a1 = hA && ((bits[a.w >> 5] >> (a.w & 31)) & 1u);
        bool b0 = hB && ((bits[b.y >> 5] >> (b.y & 31)) & 1u);
        bool b1 = hB && ((bits[b.w >> 5] >> (b.w & 31)) & 1u);

        enq(2u * pA,     (unsigned)a.x, a0);
        if (tail - head >= 64) flush64();
        enq(2u * pA + 1, (unsigned)a.z, a1);
        if (tail - head >= 64) flush64();
        enq(2u * pB,     (unsigned)b.x, b0);
        if (tail - head >= 64) flush64();
        enq(2u * pB + 1, (unsigned)b.z, b1);
        if (tail - head >= 64) flush64();

        pA += GS;
        pB += GS;
    }

    // drain
    while (tail - head >= 64) flush64();
    {
        unsigned int rem = tail - head;
        if (lane < (int)rem) {
            uint2 ent = q[(head + lane) & (QCAP - 1)];
            atomicAdd(opr + ent.y, rec_w[ent.x] * pinit[ent.y]);
        }
    }

    // tail: delay-buffer shift (independent of scatter results)
    {
        const float4* src = reinterpret_cast<const float4*>(z_buf);
        float4* dst = reinterpret_cast<float4*>(out + 3 * N);
        for (int i = gid; i < (DN - N) / 4; i += GS)
            dst[i] = src[i];
    }
}

} // namespace

extern "C" void kernel_launch(void* const* d_in, const int* in_sizes, int n_in,
                              void* d_out, int out_size, void* d_ws, size_t ws_size,
                              hipStream_t stream) {
    const float* inputs         = (const float*)d_in[0];
    const float* z_buf          = (const float*)d_in[1];
    const float* v              = (const float*)d_in[2];
    const float* r              = (const float*)d_in[3];
    const float* asc1           = (const float*)d_in[4];
    const float* asc2           = (const float*)d_in[5];
    const float* psc_rise       = (const float*)d_in[6];
    const float* psc            = (const float*)d_in[7];
    const float* rec_w          = (const float*)d_in[8];
    const int*   rec_idx        = (const int*)d_in[9];
    const float* v_th           = (const float*)d_in[10];
    const float* e_l            = (const float*)d_in[11];
    const float* v_reset        = (const float*)d_in[12];
    const float* g              = (const float*)d_in[13];
    const float* decay          = (const float*)d_in[14];
    const float* current_factor = (const float*)d_in[15];
    const float* t_ref          = (const float*)d_in[16];
    const float* k              = (const float*)d_in[17];
    const float* asc_amps       = (const float*)d_in[18];
    const float* syn_decay      = (const float*)d_in[19];
    const float* psc_initial    = (const float*)d_in[20];
    const float* voltage_scale  = (const float*)d_in[21];
    const float* voltage_offset = (const float*)d_in[22];

    float* out = (float*)d_out;
    unsigned int* bits = (unsigned int*)d_ws;          // ZB_WORDS u32

    // K1: bits + seeded psc outputs + neuron (all scatter-independent)
    pre_kernel<<<PRE_BLOCKS, 256, 0, stream>>>(
        z_buf, bits, (const float4*)inputs, psc_rise, psc, syn_decay,
        psc_initial, v, r, asc1, asc2, v_th, e_l, v_reset, g, decay,
        current_factor, t_ref, (const float2*)k, (const float2*)asc_amps,
        voltage_scale, voltage_offset, out);

    // K2: streaming scatter with compaction queue (+ shift tail)
    scatter_kernel<<<SC_GRID, SC_BLOCK, 0, stream>>>(
        rec_w, (const int4*)rec_idx, bits, psc_initial, z_buf, out);
}